// Round 10
// baseline (780.449 us; speedup 1.0000x reference)
//
#include <hip/hip_runtime.h>

#define NN 50000
#define EE 800000
#define RR 16
#define BBASES 8
#define SLOPE 0.01f
#define BCAP 16          // per-(dst,rel) slot capacity; Poisson(1): P(>=16)*800K ~ 1e-8
#define NT 64            // nodes per layer-block
#define SLICE 16384      // 128*128 elems per W slice
#define LSTRIDE (17 * SLICE)

typedef __attribute__((ext_vector_type(8))) short short8;
typedef __attribute__((ext_vector_type(4))) float f32x4;

static __device__ __forceinline__ ushort f2b(float f) {
    unsigned u = __float_as_uint(f);
    unsigned r = (u + 0x7FFF + ((u >> 16) & 1)) >> 16;
    return (ushort)r;
}
static __device__ __forceinline__ float b2f(ushort h) {
    return __uint_as_float(((unsigned)h) << 16);
}

// ---------------- x (f32) -> bf16 ----------------
__global__ __launch_bounds__(256) void k_cvt_x(
    const float* __restrict__ x, ushort* __restrict__ xb, long n4)
{
    for (long t = (long)blockIdx.x * blockDim.x + threadIdx.x; t < n4;
         t += (long)gridDim.x * blockDim.x) {
        float4 v = reinterpret_cast<const float4*>(x)[t];
        ushort4 o;
        o.x = f2b(v.x); o.y = f2b(v.y); o.z = f2b(v.z); o.w = f2b(v.w);
        reinterpret_cast<ushort4*>(xb)[t] = o;
    }
}

// ---------------- prep: stacked Wt (both layers, 17 slices each) + zero cursor + zero y1 ----
// Wt[l][r][n*128+k] = bf16( sum_b coeff_l[r,b] * basis_l[b][k*128+n] ), slice 16 = wloop^T
__global__ __launch_bounds__(256) void k_prep(
    const float* __restrict__ coeff1, const float* __restrict__ basis1,
    const float* __restrict__ coeff2, const float* __restrict__ basis2,
    const float* __restrict__ wloop1, const float* __restrict__ wloop2,
    ushort* __restrict__ Wt, int* __restrict__ curNR, float* __restrict__ y1)
{
    const int WTN = 2 * RR * SLICE;      // 524288
    const int WLN = 2 * SLICE;           // 32768
    const long total = WTN + WLN + (long)NN * RR + 128;
    for (long t = (long)blockIdx.x * blockDim.x + threadIdx.x; t < total;
         t += (long)gridDim.x * blockDim.x) {
        if (t < WTN) {
            int l = (int)(t >> 18);
            int rem = (int)(t & 262143);
            int r = rem >> 14;
            int kn = rem & 16383;
            int k = kn >> 7, n = kn & 127;
            const float* cf = l ? coeff2 : coeff1;
            const float* bs = l ? basis2 : basis1;
            float s = 0.f;
#pragma unroll
            for (int b = 0; b < BBASES; ++b)
                s += cf[r * BBASES + b] * bs[(long)b * SLICE + kn];
            Wt[(long)l * LSTRIDE + (long)r * SLICE + n * 128 + k] = f2b(s);
        } else if (t < WTN + WLN) {
            int j = (int)(t - WTN);
            int l = j >> 14;
            int kn = j & 16383;
            int k = kn >> 7, n = kn & 127;
            const float* wl = l ? wloop2 : wloop1;
            Wt[(long)l * LSTRIDE + 16 * SLICE + n * 128 + k] = f2b(wl[kn]);
        } else if (t < WTN + WLN + (long)NN * RR) {
            curNR[(int)(t - WTN - WLN)] = 0;
        } else {
            y1[(int)(t - WTN - WLN - (long)NN * RR)] = 0.f;
        }
    }
}

// ---------------- bucket edges by (dst, rel) ----------------
__global__ __launch_bounds__(256) void k_bucket(
    const int* __restrict__ src, const int* __restrict__ dst,
    const int* __restrict__ etype, int* __restrict__ curNR,
    int* __restrict__ bslot)
{
    for (long t = (long)blockIdx.x * blockDim.x + threadIdx.x; t < EE;
         t += (long)gridDim.x * blockDim.x) {
        int idx = dst[t] * RR + etype[t];
        int pos = atomicAdd(curNR + idx, 1);
        if (pos < BCAP)
            bslot[(size_t)idx * BCAP + pos] = src[t];
    }
}

// ---------------- fused layer: K-sliced gather+GEMM, 64 nodes/block ----------------
// mode 1: hbout = bf16(leakyrelu(C + bias))      (layer 1)
// mode 2: zout  = dot(C + bias, wagg) + bagg     (layer 2)
__global__ __launch_bounds__(512, 4) void k_layer(
    const ushort* __restrict__ Ain,   // [NN][128] bf16 node features
    const ushort* __restrict__ Bt,    // [17][128col][128k] bf16 stacked (slice16 = wloop^T)
    const int* __restrict__ bcnt,     // [NN*16]
    const int* __restrict__ bslot,    // [NN*16][BCAP]
    const float* __restrict__ bias,
    ushort* __restrict__ hbout,
    const float* __restrict__ wagg, const float* __restrict__ bagg,
    float* __restrict__ zout, int mode)
{
    __shared__ ushort Bs[128 * 128];   // 32 KB, [col][k] XOR-swizzled
    __shared__ ushort As[NT * 128];    // 16 KB, [node][k] XOR-swizzled
    __shared__ float zbuf[2][NT];

    int tid = threadIdx.x;
    int wid = tid >> 6, lane = tid & 63;
    int lr = lane & 15, lk = lane >> 4;
    int rowtile = wid & 3, colhalf = wid >> 2;
    int node0 = blockIdx.x * NT;
    int wid8 = wid * 8;

    // ---- preload per-wave counts & first slots for its 8 nodes x 16 rels ----
    // lane l holds flat entries j=2l (even) and j=2l+1 (odd), j = i*16 + r
    int base_j = (node0 + wid8) * 16;
    int2 cpair = *reinterpret_cast<const int2*>(bcnt + base_j + 2 * lane);
    int s_even = bslot[(size_t)(base_j + 2 * lane) * BCAP];
    int s_odd  = bslot[(size_t)(base_j + 2 * lane + 1) * BCAP];

    float4 breg[4];
    // ---- issue B(0) loads ----
    {
        const float4* srcB = reinterpret_cast<const float4*>(Bt);
#pragma unroll
        for (int it = 0; it < 4; ++it) breg[it] = srcB[it * 512 + tid];
    }

    // ---- gather helper (inlined twice via loop over phase) ----
    // gather slice r into As
#define GATHER(rr)                                                              \
    {                                                                           \
        int r_ = (rr);                                                          \
        for (int i = 0; i < 8; ++i) {                                           \
            int gn = node0 + wid8 + i;                                          \
            float ax = 0.f, ay = 0.f;                                           \
            if (r_ == 16) {                                                     \
                if (gn < NN) {                                                  \
                    unsigned u = *reinterpret_cast<const unsigned*>(            \
                        Ain + (size_t)gn * 128 + lane * 2);                     \
                    ax = b2f((ushort)(u & 0xFFFF)); ay = b2f((ushort)(u >> 16));\
                }                                                               \
            } else {                                                            \
                int jj = i * 8 + (r_ >> 1);                                     \
                int c  = (r_ & 1) ? __shfl(cpair.y, jj) : __shfl(cpair.x, jj);  \
                int s0 = (r_ & 1) ? __shfl(s_odd, jj) : __shfl(s_even, jj);     \
                c = min(c, BCAP);                                               \
                if (gn >= NN) c = 0;                                            \
                if (c > 0) {                                                    \
                    int ss = ((unsigned)s0 < NN) ? s0 : 0;                      \
                    unsigned u = *reinterpret_cast<const unsigned*>(            \
                        Ain + (size_t)ss * 128 + lane * 2);                     \
                    ax = b2f((ushort)(u & 0xFFFF)); ay = b2f((ushort)(u >> 16));\
                    for (int e = 1; e < c; ++e) {                               \
                        int s = bslot[(size_t)(gn * 16 + r_) * BCAP + e];       \
                        s = ((unsigned)s < NN) ? s : 0;                         \
                        unsigned w = *reinterpret_cast<const unsigned*>(        \
                            Ain + (size_t)s * 128 + lane * 2);                  \
                        ax += b2f((ushort)(w & 0xFFFF));                        \
                        ay += b2f((ushort)(w >> 16));                           \
                    }                                                           \
                }                                                               \
            }                                                                   \
            unsigned pk = (unsigned)f2b(ax) | ((unsigned)f2b(ay) << 16);        \
            int nl = wid8 + i;                                                  \
            *reinterpret_cast<unsigned*>(reinterpret_cast<char*>(As) +          \
                nl * 256 + ((lane * 4) ^ ((nl & 7) << 4))) = pk;                \
        }                                                                       \
    }

#define WRITEB()                                                                \
    {                                                                           \
_Pragma("unroll")                                                               \
        for (int it = 0; it < 4; ++it) {                                        \
            int g = (it * 512 + tid) * 16;                                      \
            int off = g ^ (((g >> 8) & 7) << 4);                                \
            *reinterpret_cast<float4*>(reinterpret_cast<char*>(Bs) + off) =     \
                breg[it];                                                       \
        }                                                                       \
    }

#define ISSUEB(rr)                                                              \
    {                                                                           \
        const float4* srcB = reinterpret_cast<const float4*>(                   \
            Bt + (size_t)(rr) * SLICE);                                         \
_Pragma("unroll")                                                               \
        for (int it = 0; it < 4; ++it) breg[it] = srcB[it * 512 + tid];         \
    }

    GATHER(0);
    WRITEB();            // B(0)
    ISSUEB(1);
    __syncthreads();

    f32x4 acc[4];
#pragma unroll
    for (int n = 0; n < 4; ++n) acc[n] = (f32x4){0.f, 0.f, 0.f, 0.f};

    for (int r = 0; r < 17; ++r) {
        // ---- MFMA on slice r ----
#pragma unroll
        for (int kc = 0; kc < 4; ++kc) {
            int koff = (kc * 64 + lk * 16) ^ ((lr & 7) << 4);
            short8 a = *reinterpret_cast<const short8*>(
                reinterpret_cast<const char*>(As) + (rowtile * 16 + lr) * 256 + koff);
#pragma unroll
            for (int n = 0; n < 4; ++n) {
                short8 b = *reinterpret_cast<const short8*>(
                    reinterpret_cast<const char*>(Bs) +
                    (colhalf * 64 + n * 16 + lr) * 256 + koff);
                acc[n] = __builtin_amdgcn_mfma_f32_16x16x32_bf16(a, b, acc[n], 0, 0, 0);
            }
        }
        if (r == 16) break;
        __syncthreads();
        WRITEB();                    // B(r+1), loaded during previous phase
        if (r < 15) ISSUEB(r + 2);
        GATHER(r + 1);
        __syncthreads();
    }

    // ---- epilogue ----
    if (mode == 1) {
#pragma unroll
        for (int n = 0; n < 4; ++n) {
            int col = colhalf * 64 + n * 16 + lr;
            float bc = bias[col];
#pragma unroll
            for (int j = 0; j < 4; ++j) {
                int gn = node0 + rowtile * 16 + lk * 4 + j;
                if (gn < NN) {
                    float v = acc[n][j] + bc;
                    v = v >= 0.f ? v : SLOPE * v;
                    hbout[(size_t)gn * 128 + col] = f2b(v);
                }
            }
        }
    } else {
#pragma unroll
        for (int j = 0; j < 4; ++j) {
            float p = 0.f;
#pragma unroll
            for (int n = 0; n < 4; ++n) {
                int col = colhalf * 64 + n * 16 + lr;
                p += (acc[n][j] + bias[col]) * wagg[col];
            }
            p += __shfl_xor(p, 1);
            p += __shfl_xor(p, 2);
            p += __shfl_xor(p, 4);
            p += __shfl_xor(p, 8);
            if (lr == 0) zbuf[colhalf][rowtile * 16 + lk * 4 + j] = p;
        }
        __syncthreads();
        if (tid < NT) {
            int gn = node0 + tid;
            if (gn < NN) zout[gn] = zbuf[0][tid] + zbuf[1][tid] + bagg[0];
        }
    }
#undef GATHER
#undef WRITEB
#undef ISSUEB
}

// ---------------- y1raw[j] = sum_n z[n]*wd1[n,j]  (j<100) ----------------
__global__ __launch_bounds__(256) void k_dense1(
    const float* __restrict__ z, const float* __restrict__ wd1,
    float* __restrict__ y1raw)
{
    int j = threadIdx.x & 127;
    int g = threadIdx.x >> 7;
    int rows_per_block = (NN + gridDim.x - 1) / gridDim.x;
    int n0 = blockIdx.x * rows_per_block;
    int n1 = min(NN, n0 + rows_per_block);
    if (j >= 100) return;
    float acc = 0.f;
    for (int n = n0 + g; n < n1; n += 2)
        acc += z[n] * wd1[(long)n * 100 + j];
    atomicAdd(y1raw + j, acc);
}

// ---------------- final tiny MLP head ----------------
__global__ __launch_bounds__(128) void k_final(
    const float* __restrict__ y1raw, const float* __restrict__ bd1,
    const float* __restrict__ wd2, const float* __restrict__ bd2,
    const float* __restrict__ wd3, const float* __restrict__ bd3,
    float* __restrict__ out)
{
    __shared__ float t1[100], t2[20];
    int t = threadIdx.x;
    if (t < 100) t1[t] = y1raw[t] + bd1[t];
    __syncthreads();
    if (t < 20) {
        float s = bd2[t];
        for (int j = 0; j < 100; ++j) s += t1[j] * wd2[j * 20 + t];
        t2[t] = s >= 0.f ? s : SLOPE * s;
    }
    __syncthreads();
    if (t < 10) {
        float s = bd3[t];
        for (int k = 0; k < 20; ++k) s += t2[k] * wd3[k * 10 + t];
        out[t] = s;
    }
}

extern "C" void kernel_launch(void* const* d_in, const int* in_sizes, int n_in,
                              void* d_out, int out_size, void* d_ws, size_t ws_size,
                              hipStream_t stream)
{
    const float* x      = (const float*)d_in[0];
    const int*   src    = (const int*)d_in[1];
    const int*   dst    = (const int*)d_in[2];
    const int*   etype  = (const int*)d_in[3];
    const float* coeff1 = (const float*)d_in[4];
    const float* basis1 = (const float*)d_in[5];
    const float* wloop1 = (const float*)d_in[6];
    const float* b1     = (const float*)d_in[7];
    const float* coeff2 = (const float*)d_in[8];
    const float* basis2 = (const float*)d_in[9];
    const float* wloop2 = (const float*)d_in[10];
    const float* b2     = (const float*)d_in[11];
    const float* wagg   = (const float*)d_in[12];
    const float* bagg   = (const float*)d_in[13];
    const float* wd1    = (const float*)d_in[14];
    const float* bd1    = (const float*)d_in[15];
    const float* wd2    = (const float*)d_in[16];
    const float* bd2    = (const float*)d_in[17];
    const float* wd3    = (const float*)d_in[18];
    const float* bd3    = (const float*)d_in[19];
    float* out = (float*)d_out;

    // ---- workspace layout ----
    char* p = (char*)d_ws;
    auto alloc = [&](size_t bytes) -> char* {
        char* q = p;
        p += (bytes + 255) & ~(size_t)255;
        return q;
    };
    ushort* Wt    = (ushort*)alloc(sizeof(ushort) * (size_t)2 * LSTRIDE);
    ushort* xb    = (ushort*)alloc(sizeof(ushort) * (size_t)NN * 128);
    ushort* hb    = (ushort*)alloc(sizeof(ushort) * (size_t)NN * 128);
    int*    curNR = (int*)alloc(sizeof(int) * (size_t)NN * RR);
    int*    bslot = (int*)alloc(sizeof(int) * (size_t)NN * RR * BCAP);
    float*  z     = (float*)alloc(sizeof(float) * NN);
    float*  y1    = (float*)alloc(sizeof(float) * 128);
    (void)ws_size;

    // ---- prep + bucket + convert ----
    k_prep<<<2048, 256, 0, stream>>>(coeff1, basis1, coeff2, basis2,
                                     wloop1, wloop2, Wt, curNR, y1);
    k_bucket<<<2048, 256, 0, stream>>>(src, dst, etype, curNR, bslot);
    k_cvt_x<<<2048, 256, 0, stream>>>(x, xb, (long)NN * 128 / 4);

    const int lblocks = (NN + NT - 1) / NT;
    // ---- layer 1: x -> hb ----
    k_layer<<<lblocks, 512, 0, stream>>>(
        xb, Wt, curNR, bslot, b1, hb, nullptr, nullptr, nullptr, 1);
    // ---- layer 2: hb -> z ----
    k_layer<<<lblocks, 512, 0, stream>>>(
        hb, Wt + LSTRIDE, curNR, bslot, b2, nullptr, wagg, bagg, z, 2);

    // ---- head ----
    k_dense1<<<256, 256, 0, stream>>>(z, wd1, y1);
    k_final<<<1, 128, 0, stream>>>(y1, bd1, wd2, bd2, wd3, bd3, out);
}